// Round 3
// baseline (399.263 us; speedup 1.0000x reference)
//
#include <hip/hip_runtime.h>
#include <stdint.h>

// Net_49177375539428: recursive tree-NN scorer, all-fp32.
//   k_base : base[n,:] = vecs[data[n]] @ Wd + bd ; d_score at n==pos.
//   k_tree : per-graph sequential sweep i=0..127 (par(i)>i => topo order).
//            Regular node: acc[par] += relu?(acc[i]) @ W[edge[i]] + b[edge[i]].
//            pos: store vpos (post-relu). Path node (ancestor of pos): store
//            pre-relu u into uG[slot]; path itself handled per-edge-type later.
//   k_chain: 1024 blocks (g,e): v = relu(u0 + vpos@W[e] + b[e]);
//            v = relu(u_s + v@W[ej] + b[ej]) along path; final transform+score.

#define NND 128
#define DD  128
#define GG  8
#define VD  300

typedef unsigned int u32;

#define F_RELU (1u<<16)
#define F_POS  (1u<<17)
#define F_PATH (1u<<18)

// ---------------- K1: base embeddings + d_score ----------------
__global__ void __launch_bounds__(128) k_base(
        const int* __restrict__ data, const int* __restrict__ posArr,
        const float* __restrict__ vecs, const float* __restrict__ dw,
        const float* __restrict__ db,   const float* __restrict__ sdw,
        const float* __restrict__ sb,
        float* __restrict__ base, float* __restrict__ dscore)
{
    __shared__ __align__(16) float row[VD];
    __shared__ float red[DD];
    int n = blockIdx.x, t = threadIdx.x;
    int id = data[n];
    const float4* vp = (const float4*)(vecs + (size_t)id * VD);  // 1200B rows: 16B-aligned
    for (int i = t; i < VD/4; i += 128) ((float4*)row)[i] = vp[i];
    __syncthreads();
    float acc = db[t];
    for (int d = 0; d < VD; ++d)
        acc = fmaf(row[d], dw[d*DD + t], acc);
    base[n*DD + t] = acc;
    if (n == posArr[0]){
        red[t] = acc * sdw[t];
        __syncthreads();
        for (int o = 64; o > 0; o >>= 1){ if (t < o) red[t] += red[t+o]; __syncthreads(); }
        if (t == 0) dscore[0] = sb[0] + red[0];
    }
}

// ---------------- K2: per-graph sequential vector sweep ----------------
// LDS: acc rows for nodes 1..127 (node 0 never receives contributions since
// parents are strictly greater; its row is read straight from base) + packed
// per-node descriptor. 127*128*4 + 128*4 = 65536 B exactly.
__global__ void __launch_bounds__(256) k_tree(
        const int* __restrict__ graphs, const int* __restrict__ edges,
        const int* __restrict__ posArr, const float* __restrict__ EW,
        const float* __restrict__ EB,   const float* __restrict__ base,
        float* __restrict__ vposG, float* __restrict__ uG, int* __restrict__ meta)
{
    __shared__ __align__(16) float acc[NND-1][DD];   // row r = node r+1
    __shared__ u32 desc[NND];
    int g = blockIdx.x, t = threadIdx.x;

    // init acc rows 1..127 from base
    for (int idx = t; idx < (NND-1)*DD/4; idx += 256)
        ((float4*)acc)[idx] = ((const float4*)(base + DD))[idx];

    int myPar = -1;
    if (t < NND){
        myPar = (t < NND-1) ? (t + graphs[g*NND + t]) : 0;
        desc[t] = (u32)(myPar & 0xFF) | ((u32)edges[t] << 8);
    }
    __syncthreads();
    if (t < NND-1) atomicOr(&desc[myPar], F_RELU);    // parent is internal
    if (t == 0){
        int p = posArr[0];
        atomicOr(&desc[p], F_POS);
        int c = desc[p] & 0xFF;    // parent of pos (par bits stable under concurrent Or)
        int s = 0;
        for (;;){
            atomicOr(&desc[c], F_PATH | ((u32)s << 24));
            meta[g*(NND+1) + 1 + s] = c;
            ++s;
            if (c == NND-1) break;
            c = desc[c] & 0xFF;
        }
        meta[g*(NND+1)] = s;   // path length L
    }
    __syncthreads();

    // gemv mapping: wave w (t>>6), lane l (t&63).
    //   k-group k4 = w*8 + (l&7)   -> output cols 4*k4 .. 4*k4+3   (32 groups)
    //   d-eighth  = l>>3           -> d in [16*(l>>3), +16)
    // reduction over d-eighths = shfl_xor masks 8,16,32 (all in-wave).
    int l = t & 63, w = t >> 6;
    int k4 = w*8 + (l & 7);
    int d0 = (l >> 3) * 16;

    for (int i = 0; i < NND; ++i){
        u32 dsc = desc[i];                          // block-uniform
        const float* src = (i == 0) ? base : &acc[i-1][0];
        if (dsc & F_POS){
            if (t < DD){
                float v = src[t];
                if (dsc & F_RELU) v = fmaxf(v, 0.f);
                vposG[g*DD + t] = v;
            }
        } else if (dsc & F_PATH){
            int slot = (int)(dsc >> 24);
            if (t < DD) uG[((size_t)g*NND + slot)*DD + t] = src[t];   // pre-relu
        } else {
            int par  = (int)(dsc & 0xFF);
            int edge = (int)((dsc >> 8) & 0xFF);
            bool rl  = (dsc & F_RELU) != 0;
            float ev[16];
            #pragma unroll
            for (int j = 0; j < 4; ++j){
                float4 x = *(const float4*)&src[d0 + 4*j];
                ev[4*j+0]=x.x; ev[4*j+1]=x.y; ev[4*j+2]=x.z; ev[4*j+3]=x.w;
            }
            if (rl){
                #pragma unroll
                for (int j = 0; j < 16; ++j) ev[j] = fmaxf(ev[j], 0.f);
            }
            const float* Wp = EW + (size_t)edge*(DD*DD) + (size_t)d0*DD + 4*k4;
            float s0=0.f, s1=0.f, s2=0.f, s3=0.f;
            #pragma unroll
            for (int d = 0; d < 16; ++d){
                float4 wv = *(const float4*)&Wp[d*DD];
                s0 = fmaf(ev[d], wv.x, s0);
                s1 = fmaf(ev[d], wv.y, s1);
                s2 = fmaf(ev[d], wv.z, s2);
                s3 = fmaf(ev[d], wv.w, s3);
            }
            #pragma unroll
            for (int m = 8; m <= 32; m <<= 1){
                s0 += __shfl_xor(s0, m);
                s1 += __shfl_xor(s1, m);
                s2 += __shfl_xor(s2, m);
                s3 += __shfl_xor(s3, m);
            }
            if ((l >> 3) == 0){                      // unique owner per k4
                // transform bias: + edge_biases[edge][4k4..4k4+3]
                const float4 bb = *(const float4*)&EB[(size_t)edge*DD + 4*k4];
                float4* dst = (float4*)&acc[par-1][4*k4];
                float4 o = *dst;
                o.x += s0 + bb.x; o.y += s1 + bb.y;
                o.z += s2 + bb.z; o.w += s3 + bb.w;
                *dst = o;
            }
            __syncthreads();
        }
    }
}

// ---------------- K3: per-(graph, edge-type) path chain + score ----------------
__global__ void __launch_bounds__(128) k_chain(
        const int* __restrict__ edges,
        const float* __restrict__ EW, const float* __restrict__ EB,
        const float* __restrict__ SEW,
        const float* __restrict__ vposG, const float* __restrict__ uG,
        const int* __restrict__ meta, const float* __restrict__ dscore,
        float* __restrict__ outp)
{
    __shared__ __align__(16) float v[DD];
    __shared__ float red[DD];
    int bid = blockIdx.x;
    int g = bid >> 7, e = bid & 127;
    int t = threadIdx.x;
    int L = meta[g*(NND+1)];

    v[t] = vposG[g*DD + t];
    __syncthreads();

    // step 0 at path[0]: per-e weights W[e] (the eid=-1 branch); relu (internal)
    {
        const float* W = EW + (size_t)e * DD*DD;
        float acc = uG[(size_t)g*NND*DD + t] + EB[e*DD + t];
        for (int d4 = 0; d4 < DD/4; ++d4){
            float4 vv = *(const float4*)&v[d4*4];
            acc = fmaf(vv.x, W[(d4*4+0)*DD + t], acc);
            acc = fmaf(vv.y, W[(d4*4+1)*DD + t], acc);
            acc = fmaf(vv.z, W[(d4*4+2)*DD + t], acc);
            acc = fmaf(vv.w, W[(d4*4+3)*DD + t], acc);
        }
        __syncthreads();
        v[t] = fmaxf(acc, 0.f);
        __syncthreads();
    }
    // steps 1..L-1: path[s-1] -> path[s] with edges[path[s-1]]
    for (int s = 1; s < L; ++s){
        int pn = meta[g*(NND+1) + 1 + (s-1)];
        int ej = edges[pn];
        const float* W = EW + (size_t)ej * DD*DD;
        float acc = uG[((size_t)g*NND + s)*DD + t] + EB[ej*DD + t];
        for (int d4 = 0; d4 < DD/4; ++d4){
            float4 vv = *(const float4*)&v[d4*4];
            acc = fmaf(vv.x, W[(d4*4+0)*DD + t], acc);
            acc = fmaf(vv.y, W[(d4*4+1)*DD + t], acc);
            acc = fmaf(vv.z, W[(d4*4+2)*DD + t], acc);
            acc = fmaf(vv.w, W[(d4*4+3)*DD + t], acc);
        }
        __syncthreads();
        v[t] = fmaxf(acc, 0.f);
        __syncthreads();
    }
    // final: res = emb[root] @ W[edges[root]] + b ; score = d_score + res . sew
    {
        int rn = meta[g*(NND+1) + 1 + (L-1)];   // root = 127
        int er = edges[rn];
        const float* W = EW + (size_t)er * DD*DD;
        float acc = EB[er*DD + t];
        for (int d4 = 0; d4 < DD/4; ++d4){
            float4 vv = *(const float4*)&v[d4*4];
            acc = fmaf(vv.x, W[(d4*4+0)*DD + t], acc);
            acc = fmaf(vv.y, W[(d4*4+1)*DD + t], acc);
            acc = fmaf(vv.z, W[(d4*4+2)*DD + t], acc);
            acc = fmaf(vv.w, W[(d4*4+3)*DD + t], acc);
        }
        red[t] = acc * SEW[t];
        __syncthreads();
        for (int o = 64; o > 0; o >>= 1){ if (t < o) red[t] += red[t+o]; __syncthreads(); }
        if (t == 0) outp[g*DD + e] = dscore[0] + red[0];
    }
}

extern "C" void kernel_launch(void* const* d_in, const int* in_sizes, int n_in,
                              void* d_out, int out_size, void* d_ws, size_t ws_size,
                              hipStream_t stream)
{
    const int*   data   = (const int*)d_in[0];
    /* d_in[1] = types, unused (single data_type) */
    const int*   graphs = (const int*)d_in[2];
    const int*   edges  = (const int*)d_in[3];
    const int*   posArr = (const int*)d_in[4];
    const float* vecs   = (const float*)d_in[5];
    const float* dw     = (const float*)d_in[6];
    const float* db     = (const float*)d_in[7];
    const float* ew     = (const float*)d_in[8];
    const float* eb     = (const float*)d_in[9];
    const float* sew    = (const float*)d_in[10];
    const float* sdw    = (const float*)d_in[11];
    const float* sb     = (const float*)d_in[12];

    char* ws = (char*)d_ws;
    float* base   = (float*)(ws);                               // 128*128 f32 = 64 KB
    float* vposG  = (float*)(ws + 65536);                       // 8*128 f32  = 4 KB
    float* uG     = (float*)(ws + 65536 + 4096);                // 8*128*128 f32 = 512 KB
    float* dscore = (float*)(ws + 65536 + 4096 + 524288);       // 1 f32
    int*   meta   = (int*)  (ws + 65536 + 4096 + 524288 + 256); // 8*129 ints

    float* outp = (float*)d_out;

    k_base <<<NND, 128, 0, stream>>>(data, posArr, vecs, dw, db, sdw, sb, base, dscore);
    k_tree <<<GG, 256, 0, stream>>>(graphs, edges, posArr, ew, eb, base, vposG, uG, meta);
    k_chain<<<GG*DD, 128, 0, stream>>>(edges, ew, eb, sew, vposG, uG, meta, dscore, outp);
}

// Round 4
// 348.330 us; speedup vs baseline: 1.1462x; 1.1462x over previous
//
#include <hip/hip_runtime.h>
#include <stdint.h>

// Net_49177375539428: recursive tree-NN scorer, all-fp32.
//   k_base : base[n,:] = vecs[data[n]] @ Wd + bd ; d_score at n==pos.
//   k_tree : per-graph sequential sweep i=0..127 (par(i)>i => topo order),
//            software-pipelined: W[edge[i+2]] prefetched into regs while
//            computing step i; LDS-only barrier keeps prefetch in flight.
//   k_chain: 256 blocks (8 graphs x 32 chunks of 4 edge-types). Step 0 is the
//            per-e einsum (each e its own W); shared path steps load W once
//            per block and reuse across the 4 e-rows (kills the 128x
//            redundancy of the old 1-block-per-e version).

#define NND 128
#define DD  128
#define GG  8
#define VD  300
#define CH  4          // e's per k_chain block

typedef unsigned int u32;

#define F_RELU (1u<<16)
#define F_POS  (1u<<17)
#define F_PATH (1u<<18)

// LDS-only barrier: waits ds ops, leaves global (prefetch) loads in flight.
// (HIP __syncthreads() emits s_waitcnt vmcnt(0) which would drain prefetch.)
#define SYNC_LDS() asm volatile("s_waitcnt lgkmcnt(0)\n\ts_barrier" ::: "memory")

// ---------------- K1: base embeddings + d_score ----------------
__global__ void __launch_bounds__(128) k_base(
        const int* __restrict__ data, const int* __restrict__ posArr,
        const float* __restrict__ vecs, const float* __restrict__ dw,
        const float* __restrict__ db,   const float* __restrict__ sdw,
        const float* __restrict__ sb,
        float* __restrict__ base, float* __restrict__ dscore)
{
    __shared__ __align__(16) float row[VD];
    __shared__ float red[DD];
    int n = blockIdx.x, t = threadIdx.x;
    int id = data[n];
    const float4* vp = (const float4*)(vecs + (size_t)id * VD);  // 1200B rows
    for (int i = t; i < VD/4; i += 128) ((float4*)row)[i] = vp[i];
    __syncthreads();
    float acc = db[t];
    for (int d = 0; d < VD; ++d)
        acc = fmaf(row[d], dw[d*DD + t], acc);
    base[n*DD + t] = acc;
    if (n == posArr[0]){
        red[t] = acc * sdw[t];
        __syncthreads();
        for (int o = 64; o > 0; o >>= 1){ if (t < o) red[t] += red[t+o]; __syncthreads(); }
        if (t == 0) dscore[0] = sb[0] + red[0];
    }
}

// ---------------- K2: per-graph sequential vector sweep ----------------
// LDS: acc rows for nodes 1..127 (node 0 never receives contributions) +
// packed per-node descriptor. 127*128*4 + 128*4 = 65536 B exactly.
__global__ void __launch_bounds__(256, 1) k_tree(
        const int* __restrict__ graphs, const int* __restrict__ edges,
        const int* __restrict__ posArr, const float* __restrict__ EW,
        const float* __restrict__ EB,   const float* __restrict__ base,
        float* __restrict__ vposG, float* __restrict__ uG, int* __restrict__ meta)
{
    __shared__ __align__(16) float acc[NND-1][DD];   // row r = node r+1
    __shared__ u32 desc[NND];
    int g = blockIdx.x, t = threadIdx.x;

    for (int idx = t; idx < (NND-1)*DD/4; idx += 256)
        ((float4*)acc)[idx] = ((const float4*)(base + DD))[idx];

    int myPar = -1;
    if (t < NND){
        myPar = (t < NND-1) ? (t + graphs[g*NND + t]) : 0;
        desc[t] = (u32)(myPar & 0xFF) | ((u32)edges[t] << 8);
    }
    __syncthreads();
    if (t < NND-1) atomicOr(&desc[myPar], F_RELU);    // parent is internal
    if (t == 0){
        int p = posArr[0];
        atomicOr(&desc[p], F_POS);
        int c = desc[p] & 0xFF;
        int s = 0;
        for (;;){
            atomicOr(&desc[c], F_PATH | ((u32)s << 24));
            meta[g*(NND+1) + 1 + s] = c;
            ++s;
            if (c == NND-1) break;
            c = desc[c] & 0xFF;
        }
        meta[g*(NND+1)] = s;   // path length L
    }
    __syncthreads();

    // gemv mapping: wave w (t>>6), lane l (t&63).
    //   k4 = w*8 + (l&7)  -> output cols 4*k4..+3 ; d0 = (l>>3)*16 -> 16 d's.
    int l = t & 63, w = t >> 6;
    int k4 = w*8 + (l & 7);
    int d0 = (l >> 3) * 16;
    bool owner = ((l >> 3) == 0);

    // W prefetch helper: 16 float4 of W + bias float4 into registers.
    auto pfW = [&](int edge, float4 (&wr)[16], float4& ebr){
        const float* Wp = EW + (size_t)edge*(DD*DD) + (size_t)d0*DD + 4*k4;
        #pragma unroll
        for (int d = 0; d < 16; ++d) wr[d] = *(const float4*)&Wp[d*DD];
        ebr = *(const float4*)&EB[(size_t)edge*DD + 4*k4];
    };

    auto stepGo = [&](int i, float4 (&wr)[16], float4& ebr, int iPf){
        u32 dsc = desc[i];                      // block-uniform
        const float* src = (i == 0) ? base : &acc[i-1][0];
        if (dsc & (F_POS | F_PATH)){
            if (dsc & F_POS){
                if (t < DD){
                    float v = src[t];
                    if (dsc & F_RELU) v = fmaxf(v, 0.f);
                    vposG[g*DD + t] = v;
                }
            } else {
                int slot = (int)(dsc >> 24);
                if (t < DD) uG[((size_t)g*NND + slot)*DD + t] = src[t];  // pre-relu
            }
        } else {
            int par = (int)(dsc & 0xFF);
            float ev[16];
            #pragma unroll
            for (int j = 0; j < 4; ++j){
                float4 x = *(const float4*)&src[d0 + 4*j];
                ev[4*j+0]=x.x; ev[4*j+1]=x.y; ev[4*j+2]=x.z; ev[4*j+3]=x.w;
            }
            if (dsc & F_RELU){
                #pragma unroll
                for (int j = 0; j < 16; ++j) ev[j] = fmaxf(ev[j], 0.f);
            }
            float s0=0.f, s1=0.f, s2=0.f, s3=0.f;
            #pragma unroll
            for (int d = 0; d < 16; ++d){
                s0 = fmaf(ev[d], wr[d].x, s0);
                s1 = fmaf(ev[d], wr[d].y, s1);
                s2 = fmaf(ev[d], wr[d].z, s2);
                s3 = fmaf(ev[d], wr[d].w, s3);
            }
            #pragma unroll
            for (int m = 8; m <= 32; m <<= 1){
                s0 += __shfl_xor(s0, m);
                s1 += __shfl_xor(s1, m);
                s2 += __shfl_xor(s2, m);
                s3 += __shfl_xor(s3, m);
            }
            if (owner){
                float4* dst = (float4*)&acc[par-1][4*k4];
                float4 o = *dst;
                o.x += s0 + ebr.x; o.y += s1 + ebr.y;
                o.z += s2 + ebr.z; o.w += s3 + ebr.w;
                *dst = o;
            }
        }
        if (iPf < NND){                         // uniform guard
            int eN = (int)((desc[iPf] >> 8) & 0xFF);
            pfW(eN, wr, ebr);                   // re-fill just-consumed buffer
        }
        SYNC_LDS();
    };

    float4 wA[16], wB[16], ebA, ebB;
    { int e0 = (int)((desc[0] >> 8) & 0xFF); pfW(e0, wA, ebA); }
    { int e1 = (int)((desc[1] >> 8) & 0xFF); pfW(e1, wB, ebB); }
    for (int ii = 0; ii < NND; ii += 2){
        stepGo(ii,     wA, ebA, ii+2);
        stepGo(ii + 1, wB, ebB, ii+3);
    }
}

// ---------------- K3: path chains, 4 edge-types per block ----------------
__global__ void __launch_bounds__(256, 1) k_chain(
        const int* __restrict__ edges,
        const float* __restrict__ EW, const float* __restrict__ EB,
        const float* __restrict__ SEW,
        const float* __restrict__ vposG, const float* __restrict__ uG,
        const int* __restrict__ meta, const float* __restrict__ dscore,
        float* __restrict__ outp)
{
    __shared__ __align__(16) float Vbuf[2][CH][DD];
    __shared__ float red[CH][4];
    int g = blockIdx.x >> 5, chunk = blockIdx.x & 31;
    int t = threadIdx.x, l = t & 63, w = t >> 6;
    int k4 = w*8 + (l & 7);
    int d0 = (l >> 3) * 16;
    bool owner = ((l >> 3) == 0);
    int eBase = chunk * CH;
    int L = meta[g*(NND+1)];

    // vpos slice (post-relu, from k_tree) for this lane's d-range
    float vpf[16];
    #pragma unroll
    for (int j = 0; j < 4; ++j){
        float4 x = *(const float4*)&vposG[g*DD + d0 + 4*j];
        vpf[4*j+0]=x.x; vpf[4*j+1]=x.y; vpf[4*j+2]=x.z; vpf[4*j+3]=x.w;
    }
    float4 u0 = *(const float4*)&uG[(size_t)g*NND*DD + 4*k4];

    // ---- step 0: per-e weights W[e] ----
    #pragma unroll 2
    for (int p = 0; p < CH; ++p){
        int e = eBase + p;
        const float* Wp = EW + (size_t)e*(DD*DD) + (size_t)d0*DD + 4*k4;
        float s0=0.f, s1=0.f, s2=0.f, s3=0.f;
        #pragma unroll
        for (int d = 0; d < 16; ++d){
            float4 wv = *(const float4*)&Wp[d*DD];
            s0 = fmaf(vpf[d], wv.x, s0);
            s1 = fmaf(vpf[d], wv.y, s1);
            s2 = fmaf(vpf[d], wv.z, s2);
            s3 = fmaf(vpf[d], wv.w, s3);
        }
        #pragma unroll
        for (int m = 8; m <= 32; m <<= 1){
            s0 += __shfl_xor(s0, m); s1 += __shfl_xor(s1, m);
            s2 += __shfl_xor(s2, m); s3 += __shfl_xor(s3, m);
        }
        if (owner){
            float4 bb = *(const float4*)&EB[(size_t)e*DD + 4*k4];
            float4 r;
            r.x = fmaxf(u0.x + s0 + bb.x, 0.f);
            r.y = fmaxf(u0.y + s1 + bb.y, 0.f);
            r.z = fmaxf(u0.z + s2 + bb.z, 0.f);
            r.w = fmaxf(u0.w + s3 + bb.w, 0.f);
            *(float4*)&Vbuf[0][p][4*k4] = r;
        }
    }
    __syncthreads();

    // ---- shared steps 1..L-1: one W per step, reused across CH e-rows ----
    int cur = 0;
    for (int s = 1; s < L; ++s){
        int pn = meta[g*(NND+1) + s];           // path[s-1]
        int ej = edges[pn];
        const float* Wp = EW + (size_t)ej*(DD*DD) + (size_t)d0*DD + 4*k4;
        float4 wr[16];
        #pragma unroll
        for (int d = 0; d < 16; ++d) wr[d] = *(const float4*)&Wp[d*DD];
        float4 us = *(const float4*)&uG[((size_t)g*NND + s)*DD + 4*k4];
        float4 bb = *(const float4*)&EB[(size_t)ej*DD + 4*k4];
        #pragma unroll
        for (int p = 0; p < CH; ++p){
            float ev[16];
            #pragma unroll
            for (int j = 0; j < 4; ++j){
                float4 x = *(const float4*)&Vbuf[cur][p][d0 + 4*j];
                ev[4*j+0]=x.x; ev[4*j+1]=x.y; ev[4*j+2]=x.z; ev[4*j+3]=x.w;
            }
            float s0=0.f, s1=0.f, s2=0.f, s3=0.f;
            #pragma unroll
            for (int d = 0; d < 16; ++d){
                s0 = fmaf(ev[d], wr[d].x, s0);
                s1 = fmaf(ev[d], wr[d].y, s1);
                s2 = fmaf(ev[d], wr[d].z, s2);
                s3 = fmaf(ev[d], wr[d].w, s3);
            }
            #pragma unroll
            for (int m = 8; m <= 32; m <<= 1){
                s0 += __shfl_xor(s0, m); s1 += __shfl_xor(s1, m);
                s2 += __shfl_xor(s2, m); s3 += __shfl_xor(s3, m);
            }
            if (owner){
                float4 r;
                r.x = fmaxf(us.x + s0 + bb.x, 0.f);
                r.y = fmaxf(us.y + s1 + bb.y, 0.f);
                r.z = fmaxf(us.z + s2 + bb.z, 0.f);
                r.w = fmaxf(us.w + s3 + bb.w, 0.f);
                *(float4*)&Vbuf[cur^1][p][4*k4] = r;
            }
        }
        __syncthreads();
        cur ^= 1;
    }

    // ---- final transform (root edge) + score ----
    {
        int rn = meta[g*(NND+1) + L];           // path[L-1] (= 127)
        int er = edges[rn];
        const float* Wp = EW + (size_t)er*(DD*DD) + (size_t)d0*DD + 4*k4;
        float4 wr[16];
        #pragma unroll
        for (int d = 0; d < 16; ++d) wr[d] = *(const float4*)&Wp[d*DD];
        float4 bb = *(const float4*)&EB[(size_t)er*DD + 4*k4];
        float4 sw = *(const float4*)&SEW[4*k4];
        #pragma unroll
        for (int p = 0; p < CH; ++p){
            float ev[16];
            #pragma unroll
            for (int j = 0; j < 4; ++j){
                float4 x = *(const float4*)&Vbuf[cur][p][d0 + 4*j];
                ev[4*j+0]=x.x; ev[4*j+1]=x.y; ev[4*j+2]=x.z; ev[4*j+3]=x.w;
            }
            float s0=0.f, s1=0.f, s2=0.f, s3=0.f;
            #pragma unroll
            for (int d = 0; d < 16; ++d){
                s0 = fmaf(ev[d], wr[d].x, s0);
                s1 = fmaf(ev[d], wr[d].y, s1);
                s2 = fmaf(ev[d], wr[d].z, s2);
                s3 = fmaf(ev[d], wr[d].w, s3);
            }
            #pragma unroll
            for (int m = 8; m <= 32; m <<= 1){
                s0 += __shfl_xor(s0, m); s1 += __shfl_xor(s1, m);
                s2 += __shfl_xor(s2, m); s3 += __shfl_xor(s3, m);
            }
            if (owner){
                float part = (s0 + bb.x) * sw.x + (s1 + bb.y) * sw.y
                           + (s2 + bb.z) * sw.z + (s3 + bb.w) * sw.w;
                part += __shfl_xor(part, 1);
                part += __shfl_xor(part, 2);
                part += __shfl_xor(part, 4);
                if (l == 0) red[p][w] = part;
            }
        }
        __syncthreads();
        if (t < CH)
            outp[g*DD + eBase + t] = dscore[0] + red[t][0] + red[t][1] + red[t][2] + red[t][3];
    }
}

extern "C" void kernel_launch(void* const* d_in, const int* in_sizes, int n_in,
                              void* d_out, int out_size, void* d_ws, size_t ws_size,
                              hipStream_t stream)
{
    const int*   data   = (const int*)d_in[0];
    /* d_in[1] = types, unused (single data_type) */
    const int*   graphs = (const int*)d_in[2];
    const int*   edges  = (const int*)d_in[3];
    const int*   posArr = (const int*)d_in[4];
    const float* vecs   = (const float*)d_in[5];
    const float* dw     = (const float*)d_in[6];
    const float* db     = (const float*)d_in[7];
    const float* ew     = (const float*)d_in[8];
    const float* eb     = (const float*)d_in[9];
    const float* sew    = (const float*)d_in[10];
    const float* sdw    = (const float*)d_in[11];
    const float* sb     = (const float*)d_in[12];

    char* ws = (char*)d_ws;
    float* base   = (float*)(ws);                               // 64 KB
    float* vposG  = (float*)(ws + 65536);                       // 4 KB
    float* uG     = (float*)(ws + 65536 + 4096);                // 512 KB
    float* dscore = (float*)(ws + 65536 + 4096 + 524288);       // 1 f32
    int*   meta   = (int*)  (ws + 65536 + 4096 + 524288 + 256); // 8*129 ints

    float* outp = (float*)d_out;

    k_base <<<NND, 128, 0, stream>>>(data, posArr, vecs, dw, db, sdw, sb, base, dscore);
    k_tree <<<GG, 256, 0, stream>>>(graphs, edges, posArr, ew, eb, base, vposG, uG, meta);
    k_chain<<<GG*(DD/CH), 256, 0, stream>>>(edges, ew, eb, sew, vposG, uG, meta, dscore, outp);
}